// Round 4
// baseline (760.575 us; speedup 1.0000x reference)
//
#include <hip/hip_runtime.h>
#include <cstdint>
#include <cstddef>

#define DEVINL __device__ __forceinline__

typedef float   f32x4  __attribute__((ext_vector_type(4)));
typedef float   vf4    __attribute__((ext_vector_type(4)));
typedef __bf16  bf16x8 __attribute__((ext_vector_type(8)));
typedef uint32_t u32;
typedef unsigned short u16;
typedef uint32_t u32x4 __attribute__((ext_vector_type(4)));

// Problem constants
constexpr int Bb = 2, Ss = 2048, Dd = 1024, Hh = 16;
constexpr int Mm = Bb * Ss;   // 4096 tokens

// Workspace layout (bytes), ~57 MB total:
//  0 MB : xb bf16[4096][1024] | 8 MB: Wt bf16 4x[1024][1024] | 16 MB: cos/sin
//  17 MB: Qg | 25 MB: Kg | 33 MB: Vg | 41 MB: Vtg | 49 MB: Og

DEVINL u16 f2bf(float f) {
  union { float f; u32 u; } a; a.f = f;
  u32 r = a.u + 0x7fffu + ((a.u >> 16) & 1u);   // RNE
  return (u16)(r >> 16);
}

typedef const __attribute__((address_space(1))) void* gas_t;
typedef __attribute__((address_space(3))) void* las_t;
DEVINL void gld_lds16(const void* g, void* l) {
  __builtin_amdgcn_global_load_lds((gas_t)g, (las_t)l, 16, 0, 0);
}

// ---------------- ones fill (512 MiB, pure write BW) ----------------
__global__ void fill_ones(vf4* __restrict__ p, long long n4) {
  size_t i = (size_t)blockIdx.x * blockDim.x + threadIdx.x;
  size_t stride = (size_t)gridDim.x * blockDim.x;
  const vf4 one = {1.f, 1.f, 1.f, 1.f};
  for (; i < (size_t)n4; i += stride)
    __builtin_nontemporal_store(one, p + i);
}

// ---------------- RoPE tables ----------------
__global__ void rope_table(float* __restrict__ cosT, float* __restrict__ sinT) {
  int idx = blockIdx.x * 256 + threadIdx.x;       // 65536 = 2048*32
  int s = idx >> 5, j = idx & 31;
  float freq = (float)s * exp2f(-11.0f * (float)j / 32.0f); // 2048^{-j/32}
  cosT[idx] = cosf(freq);
  sinT[idx] = sinf(freq);
}

// ---------------- cast x -> bf16 ----------------
__global__ void cast_x(const float* __restrict__ x, u16* __restrict__ xb) {
  size_t i = ((size_t)blockIdx.x * 256 + threadIdx.x) * 4;
  vf4 v = *(const vf4*)(x + i);
  union { u16 u[4]; unsigned long long q; } o;
  o.u[0] = f2bf(v.x); o.u[1] = f2bf(v.y); o.u[2] = f2bf(v.z); o.u[3] = f2bf(v.w);
  *(unsigned long long*)(xb + i) = o.q;
}

// ---------------- transpose+cast W [K][N] f32 -> [N][K] bf16 ----------------
__global__ void transpose_cast_W(const float* __restrict__ W0, const float* __restrict__ W1,
                                 const float* __restrict__ W2, const float* __restrict__ W3,
                                 u16* __restrict__ Wt) {
  __shared__ u16 tile[64][72];
  const int z = blockIdx.z;
  const float* W = (z == 0) ? W0 : (z == 1) ? W1 : (z == 2) ? W2 : W3;
  u16* Out = Wt + (size_t)z * (Dd * Dd);
  const int k0 = blockIdx.x * 64, n0 = blockIdx.y * 64;
  const int tid = threadIdx.x;
#pragma unroll
  for (int it = 0; it < 4; ++it) {
    int r = it * 16 + (tid >> 4);
    int c = (tid & 15) * 4;
    vf4 v = *(const vf4*)(W + (size_t)(k0 + r) * Dd + n0 + c);
    tile[r][c + 0] = f2bf(v.x); tile[r][c + 1] = f2bf(v.y);
    tile[r][c + 2] = f2bf(v.z); tile[r][c + 3] = f2bf(v.w);
  }
  __syncthreads();
#pragma unroll
  for (int it = 0; it < 2; ++it) {
    int c = it * 256 + tid;          // 512 chunks: 64 n-rows x 8 k-chunks
    int n = c >> 3, ck = c & 7;
    union { u16 u[8]; u32x4 q; } o;
#pragma unroll
    for (int j = 0; j < 8; ++j) o.u[j] = tile[ck * 8 + j][n];
    *(u32x4*)(Out + (size_t)(n0 + n) * Dd + k0 + ck * 8) = o.q;
  }
}

// ---------------- 128x128 bf16 MFMA GEMM core (m97-style 2-phase) ----------------
// A: [M][1024] bf16 row-major. Bt: [N][1024] bf16 (B transposed).
DEVINL void gemm_mainloop(const u16* __restrict__ A, const u16* __restrict__ Bt,
                          int m0, int n0, char* lds, f32x4 (&acc)[4][4]) {
  const int tid = threadIdx.x, lane = tid & 63;
  const int w = tid >> 6, wr = w >> 1, wc = w & 1;
  const int l15 = lane & 15, l4 = lane >> 4;
  auto stage = [&](const u16* g, int row0, int k0, char* dst) {
#pragma unroll
    for (int h2 = 0; h2 < 2; ++h2) {
      int c = h2 * 256 + tid;  // 512 chunks of 16B = 8 KB tile [128 rows][32 k]
      const char* src = (const char*)g + (size_t)(row0 + (c >> 2)) * 2048 + k0 * 2 + (c & 3) * 16;
      gld_lds16(src, dst + c * 16);
    }
  };
  stage(A, m0, 0, lds);
  stage(Bt, n0, 0, lds + 16384);
  __syncthreads();   // emits s_waitcnt vmcnt(0) lgkmcnt(0) + s_barrier
#pragma unroll 2
  for (int t = 0; t < 32; ++t) {
    const int cur = t & 1;
    char* As = lds + cur * 8192;
    char* Bs = lds + 16384 + cur * 8192;
    if (t < 31) {
      char* An = lds + (cur ^ 1) * 8192;
      char* Bn = lds + 16384 + (cur ^ 1) * 8192;
      stage(A, m0, (t + 1) * 32, An);
      stage(Bt, n0, (t + 1) * 32, Bn);
    }
    bf16x8 af[4], bfr[4];
#pragma unroll
    for (int mt = 0; mt < 4; ++mt)
      af[mt] = *(const bf16x8*)(As + (wr * 64 + mt * 16 + l15) * 64 + l4 * 16);
#pragma unroll
    for (int nt = 0; nt < 4; ++nt)
      bfr[nt] = *(const bf16x8*)(Bs + (wc * 64 + nt * 16 + l15) * 64 + l4 * 16);
#pragma unroll
    for (int mt = 0; mt < 4; ++mt)
#pragma unroll
      for (int nt = 0; nt < 4; ++nt)
        acc[mt][nt] = __builtin_amdgcn_mfma_f32_16x16x32_bf16(af[mt], bfr[nt], acc[mt][nt], 0, 0, 0);
    __syncthreads();   // drains vmcnt (stage) + lgkm; no explicit asm needed
  }
}

// EPI 0: QKV projection (3 mats), bias + RoPE(Q,K), write bf16 [B][H][S][64]
// EPI 1: out = O @ Wo + bo, write f32 [4096][1024]
template <int EPI>
__global__ __launch_bounds__(256) void gemm128(
    const u16* __restrict__ A, const u16* __restrict__ W0,
    const float* __restrict__ b0, const float* __restrict__ b1, const float* __restrict__ b2,
    const float* __restrict__ cosT, const float* __restrict__ sinT,
    u16* __restrict__ Qo, u16* __restrict__ Ko, u16* __restrict__ Vo,
    float* __restrict__ outp) {
  __shared__ __align__(16) char lds[32768];
  const int tid = threadIdx.x, lane = tid & 63;
  const int w = tid >> 6, wr = w >> 1, wc = w & 1;
  const int l15 = lane & 15, l4 = lane >> 4;

  // XCD-clustered remap: same B-panel blocks share an XCD (gridDim.y % 8 == 0)
  const int lin = blockIdx.y * 32 + blockIdx.x;
  const int xcd = lin & 7, ix = lin >> 3;
  constexpr int YPX = (EPI == 0) ? 3 : 1;          // gridDim.y / 8
  const int ytile = xcd * YPX + (ix >> 5);
  const int m0 = (ix & 31) * 128;

  int mat, n0;
  const u16* Bt;
  if (EPI == 0) { mat = ytile >> 3; n0 = (ytile & 7) * 128; Bt = W0 + (size_t)mat * (Dd * Dd); }
  else          { mat = 0;          n0 = ytile * 128;       Bt = W0; }

  f32x4 acc[4][4] = {};
  gemm_mainloop(A, Bt, m0, n0, lds, acc);

  if (EPI == 0) {
    const float* bias = (mat == 0) ? b0 : ((mat == 1) ? b1 : b2);
    u16* Out = (mat == 0) ? Qo : ((mat == 1) ? Ko : Vo);
    const bool dorope = (mat < 2);
#pragma unroll
    for (int mt = 0; mt < 4; ++mt) {
#pragma unroll
      for (int i = 0; i < 4; ++i) {
        int m = m0 + wr * 64 + mt * 16 + l4 * 4 + i;
        int bidx = m >> 11, s = m & 2047;
        float cv0 = 0.f, sv0 = 0.f, cv1 = 0.f, sv1 = 0.f;
        if (dorope) {
          cv0 = cosT[s * 32 + l15];      sv0 = sinT[s * 32 + l15];
          cv1 = cosT[s * 32 + 16 + l15]; sv1 = sinT[s * 32 + 16 + l15];
        }
#pragma unroll
        for (int nt = 0; nt < 4; ++nt) {
          int n = n0 + wc * 64 + nt * 16 + l15;
          float v = acc[mt][nt][i] + bias[n];
          float ov;
          if (dorope) {
            int np = n0 + wc * 64 + (nt ^ 2) * 16 + l15;
            float vp = acc[mt][nt ^ 2][i] + bias[np];
            float cc = (nt & 1) ? cv1 : cv0, sn = (nt & 1) ? sv1 : sv0;
            ov = (nt < 2) ? (v * cc - vp * sn)   // first half: q1*cos - q2*sin
                          : (vp * sn + v * cc);  // second half: q1*sin + q2*cos
          } else ov = v;
          int hh = n >> 6, dh = n & 63;
          Out[(((size_t)bidx * Hh + hh) * Ss + s) * 64 + dh] = f2bf(ov);
        }
      }
    }
  } else {
#pragma unroll
    for (int mt = 0; mt < 4; ++mt)
#pragma unroll
      for (int i = 0; i < 4; ++i) {
        int m = m0 + wr * 64 + mt * 16 + l4 * 4 + i;
#pragma unroll
        for (int nt = 0; nt < 4; ++nt) {
          int n = n0 + wc * 64 + nt * 16 + l15;
          outp[(size_t)m * Dd + n] = acc[mt][nt][i] + b0[n];
        }
      }
  }
}

// ---------------- V [bh][s][64] -> Vt [bh][64][s] ----------------
__global__ void transpose_v(const u16* __restrict__ Vg, u16* __restrict__ Vtg) {
  __shared__ u16 tile[64][72];
  const int s0 = blockIdx.x * 64, bh = blockIdx.y;
  const int tid = threadIdx.x;
  const u16* Vb = Vg + (size_t)bh * Ss * 64;
  u16* Vtb = Vtg + (size_t)bh * 64 * Ss;
#pragma unroll
  for (int h2 = 0; h2 < 2; ++h2) {
    int c = h2 * 256 + tid;          // 512: 64 s-rows x 8 chunks
    int r = c >> 3, ck = c & 7;
    u32x4 v = *(const u32x4*)(Vb + (size_t)(s0 + r) * 64 + ck * 8);
    const u16* t8 = (const u16*)&v;
#pragma unroll
    for (int j = 0; j < 8; ++j) tile[r][ck * 8 + j] = t8[j];
  }
  __syncthreads();
#pragma unroll
  for (int h2 = 0; h2 < 2; ++h2) {
    int c = h2 * 256 + tid;          // 512: 64 dh-rows x 8 chunks
    int dh = c >> 3, ck = c & 7;
    union { u16 u[8]; u32x4 q; } o;
#pragma unroll
    for (int j = 0; j < 8; ++j) o.u[j] = tile[ck * 8 + j][dh];
    *(u32x4*)(Vtb + (size_t)dh * Ss + s0 + ck * 8) = o.q;
  }
}

// ---------------- flash causal attention ----------------
// 1D grid 512: bh = bid&31, qtile remapped so CU pairs (q, 15-q) balance work
// and all blocks of one bh land on one XCD (bid%8 = bh%8 -> K/V L2-resident).
// Double-buffered K/V LDS (2-phase prefetch). 4 waves x 32 q-rows, KV-tile 64.
__global__ __launch_bounds__(256) void attn_kernel(
    const u16* __restrict__ Qg, const u16* __restrict__ Kg,
    const u16* __restrict__ Vtg, u16* __restrict__ Og) {
  __shared__ __align__(16) char lds[49152];
  // [0,16384): buffer0 (K 8KB | V 8KB); [16384,32768): buffer1; [32768,49152): P per-wave

  const int tid = threadIdx.x, lane = tid & 63, w = tid >> 6;
  const int l15 = lane & 15, l4 = lane >> 4;

  const int bid = blockIdx.x;
  const int bh = bid & 31;
  const int qt_raw = (bid >> 5) & 7;
  const int qtile = (bid >> 8) ? qt_raw : (15 - qt_raw);   // heavy half first
  const int q0 = qtile * 128;
  const int qw = q0 + w * 32;
  const int ntiles = 2 * qtile + 2;
  const int tdiag = qw >> 6;

  const u16*  Qb  = Qg + (size_t)bh * Ss * 64;
  const char* Kb  = (const char*)(Kg + (size_t)bh * Ss * 64);
  const char* Vtb = (const char*)(Vtg + (size_t)bh * 64 * Ss);

  bf16x8 aq[2][2];
#pragma unroll
  for (int mt = 0; mt < 2; ++mt)
#pragma unroll
    for (int kt = 0; kt < 2; ++kt)
      aq[mt][kt] = *(const bf16x8*)(Qb + (size_t)(qw + mt * 16 + l15) * 64 + kt * 32 + l4 * 8);

  f32x4 accO[2][4] = {};
  float mrow[2][4], lrow[2][4];
#pragma unroll
  for (int mt = 0; mt < 2; ++mt)
#pragma unroll
    for (int i = 0; i < 4; ++i) { mrow[mt][i] = -1e30f; lrow[mt][i] = 0.f; }

  char* pw = lds + 32768 + w * 4096;

  auto stageKV = [&](int t, char* bK, char* bV) {
    const int kv0 = t * 64;
#pragma unroll
    for (int h2 = 0; h2 < 2; ++h2) {
      int c = h2 * 256 + tid;       // 512 chunks of 16B per 8KB tile
      int r = c >> 3, ck = c & 7;
      gld_lds16(Kb + (size_t)(kv0 + r) * 128 + ((ck ^ (r & 7)) * 16), bK + c * 16);
      gld_lds16(Vtb + (size_t)r * (Ss * 2) + (size_t)kv0 * 2 + ((ck ^ (r & 7)) * 16), bV + c * 16);
    }
  };

  stageKV(0, lds, lds + 8192);
  __syncthreads();

  for (int t = 0; t < ntiles; ++t) {
    const int cur = t & 1;
    char* curb = lds + cur * 16384;
    char* nxtb = lds + (cur ^ 1) * 16384;
    if (t + 1 < ntiles) stageKV(t + 1, nxtb, nxtb + 8192);
    if (t <= tdiag) {
      const int kv0 = t * 64;
      char* ldsK = curb;
      char* ldsV = curb + 8192;

      // ---- QK^T ----
      f32x4 sf[2][4] = {};
#pragma unroll
      for (int kt = 0; kt < 2; ++kt) {
        bf16x8 bk[4];
#pragma unroll
        for (int nt = 0; nt < 4; ++nt) {
          int row = nt * 16 + l15;
          int ch = (kt * 4 + l4) ^ (row & 7);
          bk[nt] = *(const bf16x8*)(ldsK + row * 128 + ch * 16);
        }
#pragma unroll
        for (int mt = 0; mt < 2; ++mt)
#pragma unroll
          for (int nt = 0; nt < 4; ++nt)
            sf[mt][nt] = __builtin_amdgcn_mfma_f32_16x16x32_bf16(aq[mt][kt], bk[nt], sf[mt][nt], 0, 0, 0);
      }

      // ---- online softmax (row across 16 lanes; shfl_xor 1/2/4/8) ----
      const bool diag = (t == tdiag);
#pragma unroll
      for (int mt = 0; mt < 2; ++mt) {
#pragma unroll
        for (int i = 0; i < 4; ++i) {
          int row = qw + mt * 16 + l4 * 4 + i;
          float sv[4];
          float mx = -1e30f;
#pragma unroll
          for (int nt = 0; nt < 4; ++nt) {
            float xv = sf[mt][nt][i] * 0.125f;
            if (diag && (kv0 + nt * 16 + l15) > row) xv = -1e30f;
            sv[nt] = xv; mx = fmaxf(mx, xv);
          }
          mx = fmaxf(mx, __shfl_xor(mx, 1));
          mx = fmaxf(mx, __shfl_xor(mx, 2));
          mx = fmaxf(mx, __shfl_xor(mx, 4));
          mx = fmaxf(mx, __shfl_xor(mx, 8));
          float mnew = fmaxf(mrow[mt][i], mx);
          float rescale = __expf(mrow[mt][i] - mnew);
          float rs = 0.f;
          int rl = mt * 16 + l4 * 4 + i;
#pragma unroll
          for (int nt = 0; nt < 4; ++nt) {
            float p = __expf(sv[nt] - mnew);
            rs += p;
            int key = nt * 16 + l15;
            int boff = rl * 128 + (((key >> 3) ^ (rl & 7)) << 4) + (key & 7) * 2;
            *(u16*)(pw + boff) = f2bf(p);
          }
          rs += __shfl_xor(rs, 1); rs += __shfl_xor(rs, 2);
          rs += __shfl_xor(rs, 4); rs += __shfl_xor(rs, 8);
          lrow[mt][i] = lrow[mt][i] * rescale + rs;
          mrow[mt][i] = mnew;
#pragma unroll
          for (int nt = 0; nt < 4; ++nt) accO[mt][nt][i] *= rescale;
        }
      }

      // ---- PV (P wave-private LDS, Vt shared LDS) ----
#pragma unroll
      for (int ks = 0; ks < 2; ++ks) {
        bf16x8 ap[2], bv[4];
#pragma unroll
        for (int mt = 0; mt < 2; ++mt) {
          int row = mt * 16 + l15;
          int ch = (ks * 4 + l4) ^ (row & 7);
          ap[mt] = *(const bf16x8*)(pw + row * 128 + ch * 16);
        }
#pragma unroll
        for (int nt = 0; nt < 4; ++nt) {
          int row = nt * 16 + l15;
          int ch = (ks * 4 + l4) ^ (row & 7);
          bv[nt] = *(const bf16x8*)(ldsV + row * 128 + ch * 16);
        }
#pragma unroll
        for (int mt = 0; mt < 2; ++mt)
#pragma unroll
          for (int nt = 0; nt < 4; ++nt)
            accO[mt][nt] = __builtin_amdgcn_mfma_f32_16x16x32_bf16(ap[mt], bv[nt], accO[mt][nt], 0, 0, 0);
      }
    }
    __syncthreads();   // drains vmcnt (stageKV) + all LDS reads block-wide
  }

  // ---- epilogue: O/l -> bf16 [4096][1024] ----
  const int b = bh >> 4, h = bh & 15;
#pragma unroll
  for (int mt = 0; mt < 2; ++mt)
#pragma unroll
    for (int i = 0; i < 4; ++i) {
      int s = qw + mt * 16 + l4 * 4 + i;
      float inv = 1.0f / (lrow[mt][i] + 1e-10f);
      size_t rowbase = ((size_t)b * Ss + s) * Dd + h * 64;
#pragma unroll
      for (int nt = 0; nt < 4; ++nt)
        Og[rowbase + nt * 16 + l15] = f2bf(accO[mt][nt][i] * inv);
    }
}

extern "C" void kernel_launch(void* const* d_in, const int* in_sizes, int n_in,
                              void* d_out, int out_size, void* d_ws, size_t ws_size,
                              hipStream_t stream) {
  const float* x  = (const float*)d_in[0];
  const float* Wq = (const float*)d_in[1];
  const float* bq = (const float*)d_in[2];
  const float* Wk = (const float*)d_in[3];
  const float* bk = (const float*)d_in[4];
  const float* Wv = (const float*)d_in[5];
  const float* bv = (const float*)d_in[6];
  const float* Wo = (const float*)d_in[7];
  const float* bo = (const float*)d_in[8];
  float* out = (float*)d_out;

  char* ws = (char*)d_ws;                       // needs ~57 MB
  u16*   xb   = (u16*)(ws);
  u16*   Wt   = (u16*)(ws + ((size_t)8 << 20));
  float* cosT = (float*)(ws + ((size_t)16 << 20));
  float* sinT = (float*)(ws + ((size_t)16 << 20) + ((size_t)256 << 10));
  u16*   Qg   = (u16*)(ws + ((size_t)17 << 20));
  u16*   Kg   = (u16*)(ws + ((size_t)25 << 20));
  u16*   Vg   = (u16*)(ws + ((size_t)33 << 20));
  u16*   Vtg  = (u16*)(ws + ((size_t)41 << 20));
  u16*   Og   = (u16*)(ws + ((size_t)49 << 20));

  // attention_weights = ones (512 MiB, full fill this round — A/B vs side-stores)
  size_t ones_off = (size_t)Mm * Dd;                       // 4194304 floats
  vf4* onesp = (vf4*)(out + ones_off);
  const long long n4_total = ((long long)out_size - (long long)ones_off) / 4;
  fill_ones<<<2048, 256, 0, stream>>>(onesp, n4_total);

  rope_table<<<256, 256, 0, stream>>>(cosT, sinT);
  cast_x<<<(Mm * Dd) / 1024, 256, 0, stream>>>(x, xb);
  transpose_cast_W<<<dim3(16, 16, 4), 256, 0, stream>>>(Wq, Wk, Wv, Wo, Wt);

  // Q/K/V projections + bias + RoPE  (grid: 32 m-tiles x 24 n-tiles(3 mats x 8))
  gemm128<0><<<dim3(32, 24), 256, 0, stream>>>(xb, Wt, bq, bk, bv, cosT, sinT,
                                               Qg, Kg, Vg, nullptr);
  transpose_v<<<dim3(32, 32), 256, 0, stream>>>(Vg, Vtg);
  attn_kernel<<<512, 256, 0, stream>>>(Qg, Kg, Vtg, Og);
  // out = O @ Wo + bo
  gemm128<1><<<dim3(32, 8), 256, 0, stream>>>(Og, Wt + (size_t)3 * Dd * Dd,
                                              bo, nullptr, nullptr, nullptr, nullptr,
                                              nullptr, nullptr, nullptr, out);
}

// Round 5
// 731.881 us; speedup vs baseline: 1.0392x; 1.0392x over previous
//
#include <hip/hip_runtime.h>
#include <cstdint>
#include <cstddef>

#define DEVINL __device__ __forceinline__

typedef float   f32x4  __attribute__((ext_vector_type(4)));
typedef float   vf4    __attribute__((ext_vector_type(4)));
typedef __bf16  bf16x8 __attribute__((ext_vector_type(8)));
typedef uint32_t u32;
typedef unsigned short u16;
typedef uint32_t u32x4 __attribute__((ext_vector_type(4)));

// Problem constants
constexpr int Bb = 2, Ss = 2048, Dd = 1024, Hh = 16;
constexpr int Mm = Bb * Ss;   // 4096 tokens

// Workspace layout (bytes), ~57 MB total:
//  0 MB : xb bf16[4096][1024] | 8 MB: Wt bf16 4x[1024][1024] | 16 MB: cos/sin
//  17 MB: Qg | 25 MB: Kg | 33 MB: Vg | 41 MB: Vtg | 49 MB: Og

DEVINL u16 f2bf(float f) {
  union { float f; u32 u; } a; a.f = f;
  u32 r = a.u + 0x7fffu + ((a.u >> 16) & 1u);   // RNE
  return (u16)(r >> 16);
}

typedef const __attribute__((address_space(1))) void* gas_t;
typedef __attribute__((address_space(3))) void* las_t;
DEVINL void gld_lds16(const void* g, void* l) {
  __builtin_amdgcn_global_load_lds((gas_t)g, (las_t)l, 16, 0, 0);
}

// ---------------- ones fill (residual 256 MiB, pure write BW) ----------------
__global__ void fill_ones(vf4* __restrict__ p, long long n4) {
  size_t i = (size_t)blockIdx.x * blockDim.x + threadIdx.x;
  size_t stride = (size_t)gridDim.x * blockDim.x;
  const vf4 one = {1.f, 1.f, 1.f, 1.f};
  for (; i < (size_t)n4; i += stride)
    __builtin_nontemporal_store(one, p + i);
}

// ---------------- RoPE tables ----------------
__global__ void rope_table(float* __restrict__ cosT, float* __restrict__ sinT) {
  int idx = blockIdx.x * 256 + threadIdx.x;       // 65536 = 2048*32
  int s = idx >> 5, j = idx & 31;
  float freq = (float)s * exp2f(-11.0f * (float)j / 32.0f); // 2048^{-j/32}
  cosT[idx] = cosf(freq);
  sinT[idx] = sinf(freq);
}

// ---------------- cast x -> bf16 ----------------
__global__ void cast_x(const float* __restrict__ x, u16* __restrict__ xb) {
  size_t i = ((size_t)blockIdx.x * 256 + threadIdx.x) * 4;
  vf4 v = *(const vf4*)(x + i);
  union { u16 u[4]; unsigned long long q; } o;
  o.u[0] = f2bf(v.x); o.u[1] = f2bf(v.y); o.u[2] = f2bf(v.z); o.u[3] = f2bf(v.w);
  *(unsigned long long*)(xb + i) = o.q;
}

// ---------------- transpose+cast W [K][N] f32 -> [N][K] bf16 ----------------
__global__ void transpose_cast_W(const float* __restrict__ W0, const float* __restrict__ W1,
                                 const float* __restrict__ W2, const float* __restrict__ W3,
                                 u16* __restrict__ Wt) {
  __shared__ u16 tile[64][72];
  const int z = blockIdx.z;
  const float* W = (z == 0) ? W0 : (z == 1) ? W1 : (z == 2) ? W2 : W3;
  u16* Out = Wt + (size_t)z * (Dd * Dd);
  const int k0 = blockIdx.x * 64, n0 = blockIdx.y * 64;
  const int tid = threadIdx.x;
#pragma unroll
  for (int it = 0; it < 4; ++it) {
    int r = it * 16 + (tid >> 4);
    int c = (tid & 15) * 4;
    vf4 v = *(const vf4*)(W + (size_t)(k0 + r) * Dd + n0 + c);
    tile[r][c + 0] = f2bf(v.x); tile[r][c + 1] = f2bf(v.y);
    tile[r][c + 2] = f2bf(v.z); tile[r][c + 3] = f2bf(v.w);
  }
  __syncthreads();
#pragma unroll
  for (int it = 0; it < 2; ++it) {
    int c = it * 256 + tid;          // 512 chunks: 64 n-rows x 8 k-chunks
    int n = c >> 3, ck = c & 7;
    union { u16 u[8]; u32x4 q; } o;
#pragma unroll
    for (int j = 0; j < 8; ++j) o.u[j] = tile[ck * 8 + j][n];
    *(u32x4*)(Out + (size_t)(n0 + n) * Dd + k0 + ck * 8) = o.q;
  }
}

// ---------------- 128x128 bf16 MFMA GEMM core (m97-style 2-phase) ----------------
// A: [M][1024] bf16 row-major. Bt: [N][1024] bf16 (B transposed).
// Streams 2 nontemporal float4 "ones" stores per thread per K-iter (absorbed fill;
// R3/R4 A/B showed 1x/iter rides free under the MFMAs).
DEVINL void gemm_mainloop(const u16* __restrict__ A, const u16* __restrict__ Bt,
                          int m0, int n0, char* lds, f32x4 (&acc)[4][4],
                          vf4* __restrict__ onesp, size_t obase) {
  const int tid = threadIdx.x, lane = tid & 63;
  const int w = tid >> 6, wr = w >> 1, wc = w & 1;
  const int l15 = lane & 15, l4 = lane >> 4;
  auto stage = [&](const u16* g, int row0, int k0, char* dst) {
#pragma unroll
    for (int h2 = 0; h2 < 2; ++h2) {
      int c = h2 * 256 + tid;  // 512 chunks of 16B = 8 KB tile [128 rows][32 k]
      const char* src = (const char*)g + (size_t)(row0 + (c >> 2)) * 2048 + k0 * 2 + (c & 3) * 16;
      gld_lds16(src, dst + c * 16);
    }
  };
  stage(A, m0, 0, lds);
  stage(Bt, n0, 0, lds + 16384);
  __syncthreads();
  const vf4 onev = {1.f, 1.f, 1.f, 1.f};
#pragma unroll 2
  for (int t = 0; t < 32; ++t) {
    const int cur = t & 1;
    char* As = lds + cur * 8192;
    char* Bs = lds + 16384 + cur * 8192;
    if (t < 31) {
      char* An = lds + (cur ^ 1) * 8192;
      char* Bn = lds + 16384 + (cur ^ 1) * 8192;
      stage(A, m0, (t + 1) * 32, An);
      stage(Bt, n0, (t + 1) * 32, Bn);
    }
    __builtin_nontemporal_store(onev, onesp + obase + (size_t)t * 512 + tid);
    __builtin_nontemporal_store(onev, onesp + obase + (size_t)t * 512 + 256 + tid);
    bf16x8 af[4], bfr[4];
#pragma unroll
    for (int mt = 0; mt < 4; ++mt)
      af[mt] = *(const bf16x8*)(As + (wr * 64 + mt * 16 + l15) * 64 + l4 * 16);
#pragma unroll
    for (int nt = 0; nt < 4; ++nt)
      bfr[nt] = *(const bf16x8*)(Bs + (wc * 64 + nt * 16 + l15) * 64 + l4 * 16);
#pragma unroll
    for (int mt = 0; mt < 4; ++mt)
#pragma unroll
      for (int nt = 0; nt < 4; ++nt)
        acc[mt][nt] = __builtin_amdgcn_mfma_f32_16x16x32_bf16(af[mt], bfr[nt], acc[mt][nt], 0, 0, 0);
    __syncthreads();   // drains vmcnt (stage + ones stores) + lgkm
  }
}

// EPI 0: QKV projection (3 mats), bias + RoPE(Q,K), write bf16 [B][H][S][64]
// EPI 1: out = O @ Wo + bo, write f32 [4096][1024]
template <int EPI>
__global__ __launch_bounds__(256) void gemm128(
    const u16* __restrict__ A, const u16* __restrict__ W0,
    const float* __restrict__ b0, const float* __restrict__ b1, const float* __restrict__ b2,
    const float* __restrict__ cosT, const float* __restrict__ sinT,
    u16* __restrict__ Qo, u16* __restrict__ Ko, u16* __restrict__ Vo,
    float* __restrict__ outp, vf4* __restrict__ onesp) {
  __shared__ __align__(16) char lds[32768];
  const int tid = threadIdx.x, lane = tid & 63;
  const int w = tid >> 6, wr = w >> 1, wc = w & 1;
  const int l15 = lane & 15, l4 = lane >> 4;

  // XCD-clustered remap: same B-panel blocks share an XCD (gridDim.y % 8 == 0)
  const int lin = blockIdx.y * 32 + blockIdx.x;
  const int xcd = lin & 7, ix = lin >> 3;
  constexpr int YPX = (EPI == 0) ? 3 : 1;          // gridDim.y / 8
  const int ytile = xcd * YPX + (ix >> 5);
  const int m0 = (ix & 31) * 128;

  int mat, n0;
  const u16* Bt;
  if (EPI == 0) { mat = ytile >> 3; n0 = (ytile & 7) * 128; Bt = W0 + (size_t)mat * (Dd * Dd); }
  else          { mat = 0;          n0 = ytile * 128;       Bt = W0; }
  // ones coverage: gemm<0> 768 blocks * 16384 f4 = [0, 12582912);
  //                gemm<1> 256 blocks * 16384 f4 = [12582912, 16777216)
  const size_t obase = (EPI == 0 ? 0 : (size_t)12582912) + (size_t)lin * 16384;

  f32x4 acc[4][4] = {};
  gemm_mainloop(A, Bt, m0, n0, lds, acc, onesp, obase);

  if (EPI == 0) {
    const float* bias = (mat == 0) ? b0 : ((mat == 1) ? b1 : b2);
    u16* Out = (mat == 0) ? Qo : ((mat == 1) ? Ko : Vo);
    const bool dorope = (mat < 2);
#pragma unroll
    for (int mt = 0; mt < 4; ++mt) {
#pragma unroll
      for (int i = 0; i < 4; ++i) {
        int m = m0 + wr * 64 + mt * 16 + l4 * 4 + i;
        int bidx = m >> 11, s = m & 2047;
        float cv0 = 0.f, sv0 = 0.f, cv1 = 0.f, sv1 = 0.f;
        if (dorope) {
          cv0 = cosT[s * 32 + l15];      sv0 = sinT[s * 32 + l15];
          cv1 = cosT[s * 32 + 16 + l15]; sv1 = sinT[s * 32 + 16 + l15];
        }
#pragma unroll
        for (int nt = 0; nt < 4; ++nt) {
          int n = n0 + wc * 64 + nt * 16 + l15;
          float v = acc[mt][nt][i] + bias[n];
          float ov;
          if (dorope) {
            int np = n0 + wc * 64 + (nt ^ 2) * 16 + l15;
            float vp = acc[mt][nt ^ 2][i] + bias[np];
            float cc = (nt & 1) ? cv1 : cv0, sn = (nt & 1) ? sv1 : sv0;
            ov = (nt < 2) ? (v * cc - vp * sn)   // first half: q1*cos - q2*sin
                          : (vp * sn + v * cc);  // second half: q1*sin + q2*cos
          } else ov = v;
          int hh = n >> 6, dh = n & 63;
          Out[(((size_t)bidx * Hh + hh) * Ss + s) * 64 + dh] = f2bf(ov);
        }
      }
    }
  } else {
#pragma unroll
    for (int mt = 0; mt < 4; ++mt)
#pragma unroll
      for (int i = 0; i < 4; ++i) {
        int m = m0 + wr * 64 + mt * 16 + l4 * 4 + i;
#pragma unroll
        for (int nt = 0; nt < 4; ++nt) {
          int n = n0 + wc * 64 + nt * 16 + l15;
          outp[(size_t)m * Dd + n] = acc[mt][nt][i] + b0[n];
        }
      }
  }
}

// ---------------- V [bh][s][64] -> Vt [bh][64][s] ----------------
__global__ void transpose_v(const u16* __restrict__ Vg, u16* __restrict__ Vtg) {
  __shared__ u16 tile[64][72];
  const int s0 = blockIdx.x * 64, bh = blockIdx.y;
  const int tid = threadIdx.x;
  const u16* Vb = Vg + (size_t)bh * Ss * 64;
  u16* Vtb = Vtg + (size_t)bh * 64 * Ss;
#pragma unroll
  for (int h2 = 0; h2 < 2; ++h2) {
    int c = h2 * 256 + tid;          // 512: 64 s-rows x 8 chunks
    int r = c >> 3, ck = c & 7;
    u32x4 v = *(const u32x4*)(Vb + (size_t)(s0 + r) * 64 + ck * 8);
    const u16* t8 = (const u16*)&v;
#pragma unroll
    for (int j = 0; j < 8; ++j) tile[r][ck * 8 + j] = t8[j];
  }
  __syncthreads();
#pragma unroll
  for (int h2 = 0; h2 < 2; ++h2) {
    int c = h2 * 256 + tid;          // 512: 64 dh-rows x 8 chunks
    int dh = c >> 3, ck = c & 7;
    union { u16 u[8]; u32x4 q; } o;
#pragma unroll
    for (int j = 0; j < 8; ++j) o.u[j] = tile[ck * 8 + j][dh];
    *(u32x4*)(Vtb + (size_t)dh * Ss + s0 + ck * 8) = o.q;
  }
}

// ---------------- flash causal attention (de-staged: K/V direct from L2) -------
// K/V per bh = 512 KB, L2-resident (bh -> XCD clustering via bid%8 = bh%8).
// No LDS staging, no __syncthreads: waves fully independent. P round-trip stays
// in wave-private LDS (same-wave DS ordering, validated on HW in R3/R4).
// 1D grid 512: CU pairs (qtile, 15-qtile) balance causal work.
__global__ __launch_bounds__(256) void attn_kernel(
    const u16* __restrict__ Qg, const u16* __restrict__ Kg,
    const u16* __restrict__ Vtg, u16* __restrict__ Og) {
  __shared__ __align__(16) char lds[16384];   // 4 KB per-wave P [32 q][128B swizzled]

  const int tid = threadIdx.x, lane = tid & 63, w = tid >> 6;
  const int l15 = lane & 15, l4 = lane >> 4;

  const int bid = blockIdx.x;
  const int bh = bid & 31;
  const int qt_raw = (bid >> 5) & 7;
  const int qtile = (bid >> 8) ? qt_raw : (15 - qt_raw);   // heavy half first
  const int qw = qtile * 128 + w * 32;
  const int tdiag = qw >> 6;

  const u16*  Qb  = Qg + (size_t)bh * Ss * 64;
  const char* Kb  = (const char*)(Kg + (size_t)bh * Ss * 64);
  const char* Vtb = (const char*)(Vtg + (size_t)bh * 64 * Ss);

  bf16x8 aq[2][2];
#pragma unroll
  for (int mt = 0; mt < 2; ++mt)
#pragma unroll
    for (int kt = 0; kt < 2; ++kt)
      aq[mt][kt] = *(const bf16x8*)(Qb + (size_t)(qw + mt * 16 + l15) * 64 + kt * 32 + l4 * 8);

  f32x4 accO[2][4] = {};
  float mrow[2][4], lrow[2][4];
#pragma unroll
  for (int mt = 0; mt < 2; ++mt)
#pragma unroll
    for (int i = 0; i < 4; ++i) { mrow[mt][i] = -1e30f; lrow[mt][i] = 0.f; }

  char* pw = lds + w * 4096;

  for (int t = 0; t <= tdiag; ++t) {
    const int kv0 = t * 64;

    // ---- QK^T (K fragments direct from global; 16 fully-consumed 128B lines each)
    f32x4 sf[2][4] = {};
#pragma unroll
    for (int kt = 0; kt < 2; ++kt) {
      bf16x8 bk[4];
#pragma unroll
      for (int nt = 0; nt < 4; ++nt)
        bk[nt] = *(const bf16x8*)(Kb + (size_t)(kv0 + nt * 16 + l15) * 128 + kt * 64 + l4 * 16);
      __builtin_amdgcn_s_setprio(1);
#pragma unroll
      for (int mt = 0; mt < 2; ++mt)
#pragma unroll
        for (int nt = 0; nt < 4; ++nt)
          sf[mt][nt] = __builtin_amdgcn_mfma_f32_16x16x32_bf16(aq[mt][kt], bk[nt], sf[mt][nt], 0, 0, 0);
      __builtin_amdgcn_s_setprio(0);
    }

    // ---- online softmax (row across 16 lanes; shfl_xor 1/2/4/8) ----
    const bool diag = (t == tdiag);
#pragma unroll
    for (int mt = 0; mt < 2; ++mt) {
#pragma unroll
      for (int i = 0; i < 4; ++i) {
        int row = qw + mt * 16 + l4 * 4 + i;
        float sv[4];
        float mx = -1e30f;
#pragma unroll
        for (int nt = 0; nt < 4; ++nt) {
          float xv = sf[mt][nt][i] * 0.125f;
          if (diag && (kv0 + nt * 16 + l15) > row) xv = -1e30f;
          sv[nt] = xv; mx = fmaxf(mx, xv);
        }
        mx = fmaxf(mx, __shfl_xor(mx, 1));
        mx = fmaxf(mx, __shfl_xor(mx, 2));
        mx = fmaxf(mx, __shfl_xor(mx, 4));
        mx = fmaxf(mx, __shfl_xor(mx, 8));
        float mnew = fmaxf(mrow[mt][i], mx);
        float rescale = __expf(mrow[mt][i] - mnew);
        float rs = 0.f;
        int rl = mt * 16 + l4 * 4 + i;
#pragma unroll
        for (int nt = 0; nt < 4; ++nt) {
          float p = __expf(sv[nt] - mnew);
          rs += p;
          int key = nt * 16 + l15;
          int boff = rl * 128 + (((key >> 3) ^ (rl & 7)) << 4) + (key & 7) * 2;
          *(u16*)(pw + boff) = f2bf(p);
        }
        rs += __shfl_xor(rs, 1); rs += __shfl_xor(rs, 2);
        rs += __shfl_xor(rs, 4); rs += __shfl_xor(rs, 8);
        lrow[mt][i] = lrow[mt][i] * rescale + rs;
        mrow[mt][i] = mnew;
#pragma unroll
        for (int nt = 0; nt < 4; ++nt) accO[mt][nt][i] *= rescale;
      }
    }

    // ---- PV (P from wave-private LDS; Vt fragments direct from global) ----
#pragma unroll
    for (int ks = 0; ks < 2; ++ks) {
      bf16x8 ap[2], bv[4];
#pragma unroll
      for (int mt = 0; mt < 2; ++mt) {
        int row = mt * 16 + l15;
        int ch = (ks * 4 + l4) ^ (row & 7);
        ap[mt] = *(const bf16x8*)(pw + row * 128 + ch * 16);
      }
#pragma unroll
      for (int nt = 0; nt < 4; ++nt)
        bv[nt] = *(const bf16x8*)(Vtb + (size_t)(nt * 16 + l15) * (Ss * 2) + (size_t)kv0 * 2 + ks * 64 + l4 * 16);
      __builtin_amdgcn_s_setprio(1);
#pragma unroll
      for (int mt = 0; mt < 2; ++mt)
#pragma unroll
        for (int nt = 0; nt < 4; ++nt)
          accO[mt][nt] = __builtin_amdgcn_mfma_f32_16x16x32_bf16(ap[mt], bv[nt], accO[mt][nt], 0, 0, 0);
      __builtin_amdgcn_s_setprio(0);
    }
  }

  // ---- epilogue: O/l -> bf16 [4096][1024] ----
  const int b = bh >> 4, h = bh & 15;
#pragma unroll
  for (int mt = 0; mt < 2; ++mt)
#pragma unroll
    for (int i = 0; i < 4; ++i) {
      int s = qw + mt * 16 + l4 * 4 + i;
      float inv = 1.0f / (lrow[mt][i] + 1e-10f);
      size_t rowbase = ((size_t)b * Ss + s) * Dd + h * 64;
#pragma unroll
      for (int nt = 0; nt < 4; ++nt)
        Og[rowbase + nt * 16 + l15] = f2bf(accO[mt][nt][i] * inv);
    }
}

extern "C" void kernel_launch(void* const* d_in, const int* in_sizes, int n_in,
                              void* d_out, int out_size, void* d_ws, size_t ws_size,
                              hipStream_t stream) {
  const float* x  = (const float*)d_in[0];
  const float* Wq = (const float*)d_in[1];
  const float* bq = (const float*)d_in[2];
  const float* Wk = (const float*)d_in[3];
  const float* bk = (const float*)d_in[4];
  const float* Wv = (const float*)d_in[5];
  const float* bv = (const float*)d_in[6];
  const float* Wo = (const float*)d_in[7];
  const float* bo = (const float*)d_in[8];
  float* out = (float*)d_out;

  char* ws = (char*)d_ws;                       // needs ~57 MB
  u16*   xb   = (u16*)(ws);
  u16*   Wt   = (u16*)(ws + ((size_t)8 << 20));
  float* cosT = (float*)(ws + ((size_t)16 << 20));
  float* sinT = (float*)(ws + ((size_t)16 << 20) + ((size_t)256 << 10));
  u16*   Qg   = (u16*)(ws + ((size_t)17 << 20));
  u16*   Kg   = (u16*)(ws + ((size_t)25 << 20));
  u16*   Vg   = (u16*)(ws + ((size_t)33 << 20));
  u16*   Vtg  = (u16*)(ws + ((size_t)41 << 20));
  u16*   Og   = (u16*)(ws + ((size_t)49 << 20));

  // attention_weights = ones. 512 MiB = 33,554,432 float4.
  // [0, 12582912) f4: gemm<0> side-stores; [12582912, 16777216): gemm<1>;
  // [16777216, 33554432): fill_ones (256 MiB).
  size_t ones_off = (size_t)Mm * Dd;                       // 4194304 floats
  vf4* onesp = (vf4*)(out + ones_off);
  const long long n4_total = ((long long)out_size - (long long)ones_off) / 4;
  const long long n4_side  = 16777216;
  fill_ones<<<2048, 256, 0, stream>>>(onesp + n4_side, n4_total - n4_side);

  rope_table<<<256, 256, 0, stream>>>(cosT, sinT);
  cast_x<<<(Mm * Dd) / 1024, 256, 0, stream>>>(x, xb);
  transpose_cast_W<<<dim3(16, 16, 4), 256, 0, stream>>>(Wq, Wk, Wv, Wo, Wt);

  // Q/K/V projections + bias + RoPE  (grid: 32 m-tiles x 24 n-tiles(3 mats x 8))
  gemm128<0><<<dim3(32, 24), 256, 0, stream>>>(xb, Wt, bq, bk, bv, cosT, sinT,
                                               Qg, Kg, Vg, nullptr, onesp);
  transpose_v<<<dim3(32, 32), 256, 0, stream>>>(Vg, Vtg);
  attn_kernel<<<512, 256, 0, stream>>>(Qg, Kg, Vtg, Og);
  // out = O @ Wo + bo
  gemm128<1><<<dim3(32, 8), 256, 0, stream>>>(Og, Wt + (size_t)3 * Dd * Dd,
                                              bo, nullptr, nullptr, nullptr, nullptr,
                                              nullptr, nullptr, nullptr, out, onesp);
}